// Round 8
// baseline (252.865 us; speedup 1.0000x reference)
//
#include <hip/hip_runtime.h>
#include <math.h>

#define HW 262144          // 512*512
#define NB 4
#define NC 4
#define ND 32
#define NPIX (NB * HW)     // 1048576
#define NG 262144          // float4 pixel-groups (NPIX/4)
#define EPSF 1e-8f

// ws header (floats):
#define OFF_SUMS    0      // 1024
#define OFF_COUNTS  1024   // 32
#define OFF_CENTERS 1056   // 1024
#define OFF_CNORM   2080   // 32
#define OFF_PART    2112   // 256
#define HDR_BYTES   9472
// byte offsets after header:
#define OFF_REC     HDR_BYTES                     // u32[NG]    1 MB
#define OFF_CPK     (OFF_REC + 4L * NG)           // uint4[NG]  4 MB (bf16 conf pairs)
#define OFF_CEM     (OFF_CPK + 16L * NG)          // float4[NG] 4 MB
#define OFF_CEA     (OFF_CEM + 16L * NG)          // float4[NG] 4 MB
#define OFF_PF      (OFF_CEA + 16L * NG)          // bf16 [b][d][px] 64 MB
#define WS_NEED_PF  (OFF_PF + 2L * NB * ND * HW)  // ~77 MB

#define ELEM(v,e) ((e)==0?(v).x:(e)==1?(v).y:(e)==2?(v).z:(v).w)
#define W32(q,i)  ((i)==0?(q).x:(i)==1?(q).y:(i)==2?(q).z:(q).w)

__device__ __forceinline__ float wave_sum64(float v) {
#pragma unroll
  for (int off = 32; off > 0; off >>= 1) v += __shfl_xor(v, off, 64);
  return v;
}
__device__ __forceinline__ unsigned short f2bf(float f) {  // RNE
  unsigned u = __float_as_uint(f);
  return (unsigned short)((u + 0x7fffu + ((u >> 16) & 1u)) >> 16);
}
__device__ __forceinline__ float bf2f(unsigned short s) {
  return __uint_as_float(((unsigned)s) << 16);
}

// accumulate 4 px: RUW = rec word, CK = conf uint4, Q0/Q1 = uint4 bf16-pair
// pf data for ch0/ch1 (8 px); HI selects px 0-3 (words 0,1) or 4-7 (2,3).
#define ACC4(RUW, CK, Q0, Q1, HI)                                          \
  {                                                                        \
    _Pragma("unroll")                                                      \
    for (int e = 0; e < 4; ++e) {                                          \
      unsigned r_ = ((RUW) >> (8 * e)) & 0xffu;                            \
      unsigned pk_ = W32((CK), e);                                         \
      int hm_ = r_ & 3, ha_ = (r_ >> 2) & 3;                               \
      float cm_ = __uint_as_float(pk_ << 16);                              \
      float ca_ = __uint_as_float(pk_ & 0xffff0000u);                      \
      unsigned w0_ = W32((Q0), (HI) * 2 + (e >> 1));                       \
      unsigned w1_ = W32((Q1), (HI) * 2 + (e >> 1));                       \
      float p0v = __uint_as_float((e & 1) ? (w0_ & 0xffff0000u) : (w0_ << 16)); \
      float p1v = __uint_as_float((e & 1) ? (w1_ & 0xffff0000u) : (w1_ << 16)); \
      float w0 = hm_ == 0 ? cm_ : 0.f, w1 = hm_ == 1 ? cm_ : 0.f;          \
      float w2 = hm_ == 2 ? cm_ : 0.f, w3 = hm_ == 3 ? cm_ : 0.f;          \
      float u0 = ha_ == 0 ? ca_ : 0.f, u1 = ha_ == 1 ? ca_ : 0.f;          \
      float u2 = ha_ == 2 ? ca_ : 0.f, u3 = ha_ == 3 ? ca_ : 0.f;          \
      acc[0][0] = fmaf(w0, p0v, acc[0][0]);                                \
      acc[0][1] = fmaf(w1, p0v, acc[0][1]);                                \
      acc[0][2] = fmaf(w2, p0v, acc[0][2]);                                \
      acc[0][3] = fmaf(w3, p0v, acc[0][3]);                                \
      acc[0][4] = fmaf(u0, p0v, acc[0][4]);                                \
      acc[0][5] = fmaf(u1, p0v, acc[0][5]);                                \
      acc[0][6] = fmaf(u2, p0v, acc[0][6]);                                \
      acc[0][7] = fmaf(u3, p0v, acc[0][7]);                                \
      acc[1][0] = fmaf(w0, p1v, acc[1][0]);                                \
      acc[1][1] = fmaf(w1, p1v, acc[1][1]);                                \
      acc[1][2] = fmaf(w2, p1v, acc[1][2]);                                \
      acc[1][3] = fmaf(w3, p1v, acc[1][3]);                                \
      acc[1][4] = fmaf(u0, p1v, acc[1][4]);                                \
      acc[1][5] = fmaf(u1, p1v, acc[1][5]);                                \
      acc[1][6] = fmaf(u2, p1v, acc[1][6]);                                \
      acc[1][7] = fmaf(u3, p1v, acc[1][7]);                                \
    }                                                                      \
  }

// -------- Pass A2s: per-pixel stats only (R2-proven shape) --------
__global__ __launch_bounds__(256) void passA2s(
    const float* __restrict__ pm, const float* __restrict__ pa,
    unsigned* __restrict__ recu, uint4* __restrict__ cpk4,
    float4* __restrict__ cem4, float4* __restrict__ cea4) {
  int p4 = blockIdx.x * 256 + threadIdx.x;
  int b = p4 >> 16;
  int px4 = p4 & 0xFFFF;
  const float4* xb = (const float4*)pm + (((long)b * NC) << 16) + px4;
  const float4* yb = (const float4*)pa + (((long)b * NC) << 16) + px4;
  float4 X0 = xb[0], X1 = xb[1 << 16], X2 = xb[2 << 16], X3 = xb[3 << 16];
  float4 Y0 = yb[0], Y1 = yb[1 << 16], Y2 = yb[2 << 16], Y3 = yb[3 << 16];
  float4 cem, cea;
  uint4 cpk;
  unsigned ru = 0;
#pragma unroll
  for (int e = 0; e < 4; ++e) {
    float x0 = ELEM(X0, e), x1 = ELEM(X1, e), x2 = ELEM(X2, e), x3 = ELEM(X3, e);
    float y0 = ELEM(Y0, e), y1 = ELEM(Y1, e), y2 = ELEM(Y2, e), y3 = ELEM(Y3, e);
    int hm = 0; float bm = x0;
    if (x1 > bm) { bm = x1; hm = 1; }
    if (x2 > bm) { bm = x2; hm = 2; }
    if (x3 > bm) { bm = x3; hm = 3; }
    int ha = 0; float ba = y0;
    if (y1 > ba) { ba = y1; ha = 1; }
    if (y2 > ba) { ba = y2; ha = 2; }
    if (y3 > ba) { ba = y3; ha = 3; }
    float sem = expf(x0 - bm) + expf(x1 - bm) + expf(x2 - bm) + expf(x3 - bm);
    float sea = expf(y0 - ba) + expf(y1 - ba) + expf(y2 - ba) + expf(y3 - ba);
    float confm = 1.0f / sem, confa = 1.0f / sea;
    int mk = (confm >= confa) ? 1 : 0;
    int lab = mk ? hm : ha;
    float xl = lab == 0 ? x0 : lab == 1 ? x1 : lab == 2 ? x2 : x3;
    float yl = lab == 0 ? y0 : lab == 1 ? y1 : lab == 2 ? y2 : y3;
    float vem = bm - xl + logf(sem);
    float vea = ba - yl + logf(sea);
    unsigned pk = (unsigned)f2bf(confm) | ((unsigned)f2bf(confa) << 16);
    if (e == 0) { cem.x = vem; cea.x = vea; cpk.x = pk; }
    if (e == 1) { cem.y = vem; cea.y = vea; cpk.y = pk; }
    if (e == 2) { cem.z = vem; cea.z = vea; cpk.z = pk; }
    if (e == 3) { cem.w = vem; cea.w = vea; cpk.w = pk; }
    ru |= (unsigned)(hm | (ha << 2) | (mk << 4)) << (8 * e);
  }
  cem4[p4] = cem; cea4[p4] = cea; cpk4[p4] = cpk; recu[p4] = ru;
}

// -------- pfWrite: materialize bf16 pseudo-feature (pure streamer) -------
// (256,2): 128-VGPR cap so unroll-8 can hold 16 float4 loads in flight.
__global__ __launch_bounds__(256, 2) void pfWrite(
    const float* __restrict__ fm, const float* __restrict__ fa,
    const unsigned* __restrict__ recu, unsigned short* __restrict__ pf) {
  int p4 = blockIdx.x * 256 + threadIdx.x;
  int b = p4 >> 16;
  int px4 = p4 & 0xFFFF;
  unsigned ru = recu[p4];
  int mk0 = (ru >> 4) & 1, mk1 = (ru >> 12) & 1;
  int mk2 = (ru >> 20) & 1, mk3 = (ru >> 28) & 1;
  const float4* fmb = (const float4*)fm + (((long)(b * ND)) << 16) + px4;
  const float4* fab = (const float4*)fa + (((long)(b * ND)) << 16) + px4;
  ushort4* pfb = (ushort4*)pf + (((long)(b * ND)) << 16) + px4;
#pragma unroll 8
  for (int d = 0; d < ND; ++d) {
    float4 vm = fmb[(long)d << 16];
    float4 va = fab[(long)d << 16];
    ushort4 s;
    s.x = f2bf(mk0 ? vm.x : va.x);
    s.y = f2bf(mk1 ? vm.y : va.y);
    s.z = f2bf(mk2 ? vm.z : va.z);
    s.w = f2bf(mk3 ? vm.w : va.w);
    pfb[(long)d << 16] = s;
  }
}

// -------- countK: per-(b,map,cls) pixel counts from recu --------
__global__ __launch_bounds__(256) void countK(const unsigned* __restrict__ recu,
                                              float* __restrict__ counts) {
  int b = blockIdx.y;
  int t = blockIdx.x * 256 + threadIdx.x;   // grid.x=32 -> t in [0,8192)
  float c[8];
#pragma unroll
  for (int j = 0; j < 8; ++j) c[j] = 0.f;
#pragma unroll
  for (int k = 0; k < 8; ++k) {
    unsigned ru = recu[(b << 16) + t + k * 8192];
#pragma unroll
    for (int e = 0; e < 4; ++e) {
      unsigned r = (ru >> (8 * e)) & 0xffu;
      int hm = r & 3, ha = (r >> 2) & 3;
      c[0] += hm == 0 ? 1.f : 0.f; c[1] += hm == 1 ? 1.f : 0.f;
      c[2] += hm == 2 ? 1.f : 0.f; c[3] += hm == 3 ? 1.f : 0.f;
      c[4] += ha == 0 ? 1.f : 0.f; c[5] += ha == 1 ? 1.f : 0.f;
      c[6] += ha == 2 ? 1.f : 0.f; c[7] += ha == 3 ? 1.f : 0.f;
    }
  }
  int lane = threadIdx.x & 63;
#pragma unroll
  for (int j = 0; j < 8; ++j) {
    float v = wave_sum64(c[j]);
    if (lane == 0) atomicAdd(&counts[(j >> 2) * 16 + b * 4 + (j & 3)], v);
  }
}

// -------- Pass B (pf): center sums from bf16 pf, 2 ch/wave --------
// grid (128, 16 = b*4+cg), block 256 (4 waves); 512 groups/block.
// (256,2): unroll-2 body = ~36 load regs + 16 acc + addr ~= 70 <= 128 cap.
__global__ __launch_bounds__(256, 2) void passBpf(
    const unsigned short* __restrict__ pf, const unsigned* __restrict__ recu,
    const uint4* __restrict__ cpk4, float* __restrict__ sums) {
  int b = blockIdx.y >> 2;
  int cg = blockIdx.y & 3;
  int wave = threadIdx.x >> 6;
  int lane = threadIdx.x & 63;
  int ch0 = cg * 8 + wave * 2;

  int pair0 = blockIdx.x * 256 + lane;   // uint4-pair units (2 groups = 8 px)
  const uint4* q0p = (const uint4*)pf + (((long)(b * ND + ch0)) << 15) + pair0;
  const uint4* q1p = q0p + (1L << 15);
  const uint2* rr2 = (const uint2*)recu + ((long)b << 15) + pair0;
  const uint4* ckp = cpk4 + ((long)b << 16) + 2 * (long)pair0;

  float acc[2][8];
#pragma unroll
  for (int c = 0; c < 2; ++c)
#pragma unroll
    for (int j = 0; j < 8; ++j) acc[c][j] = 0.f;

#pragma unroll 2
  for (int it = 0; it < 4; ++it) {
    int o = it * 64;
    uint4 Q0 = q0p[o];
    uint4 Q1 = q1p[o];
    uint2 rr = rr2[o];
    uint4 ckA = ckp[2 * o];
    uint4 ckB = ckp[2 * o + 1];
    ACC4(rr.x, ckA, Q0, Q1, 0);
    ACC4(rr.y, ckB, Q0, Q1, 1);
  }

#pragma unroll
  for (int c = 0; c < 2; ++c)
#pragma unroll
    for (int j = 0; j < 8; ++j) {
      float v = wave_sum64(acc[c][j]);
      if (lane == 0) {
        int map = j >> 2, cls = j & 3;
        atomicAdd(&sums[((map * NB + b) * NC + cls) * ND + ch0 + c], v);
      }
    }
}

// -------- Pass B (f32 fallback): R2-proven structure (counts via countK) --
__global__ __launch_bounds__(256) void passBf32(
    const float* __restrict__ fm, const float* __restrict__ fa,
    const unsigned* __restrict__ recu, const uint4* __restrict__ cpk4,
    float* __restrict__ sums) {
  int b = blockIdx.y >> 2;
  int cg = blockIdx.y & 3;
  int wave = threadIdx.x >> 6;
  int lane = threadIdx.x & 63;
  int ch0 = cg * 8 + wave * 2;

  int base4 = blockIdx.x * 512 + lane;
  const float4* f0m = (const float4*)fm + (((long)(b * ND + ch0)) << 16) + base4;
  const float4* f0a = (const float4*)fa + (((long)(b * ND + ch0)) << 16) + base4;
  const float4* f1m = f0m + (1L << 16);
  const float4* f1a = f0a + (1L << 16);
  const unsigned* rup = recu + (b << 16) + base4;
  const uint4* cpp = cpk4 + (b << 16) + base4;

  float acc[2][8];
#pragma unroll
  for (int c = 0; c < 2; ++c)
#pragma unroll
    for (int j = 0; j < 8; ++j) acc[c][j] = 0.f;

#pragma unroll 2
  for (int it = 0; it < 8; ++it) {
    int i4 = it * 64;
    unsigned ru = rup[i4];
    uint4 ck = cpp[i4];
    float4 v0m = f0m[i4], v0a = f0a[i4];
    float4 v1m = f1m[i4], v1a = f1a[i4];
#pragma unroll
    for (int e = 0; e < 4; ++e) {
      unsigned r = (ru >> (8 * e)) & 0xffu;
      unsigned pk = W32(ck, e);
      int hm = r & 3, ha = (r >> 2) & 3, mk = (r >> 4) & 1;
      float cm = __uint_as_float(pk << 16);
      float ca = __uint_as_float(pk & 0xffff0000u);
      float w0 = hm == 0 ? cm : 0.f, w1 = hm == 1 ? cm : 0.f;
      float w2 = hm == 2 ? cm : 0.f, w3 = hm == 3 ? cm : 0.f;
      float u0 = ha == 0 ? ca : 0.f, u1 = ha == 1 ? ca : 0.f;
      float u2 = ha == 2 ? ca : 0.f, u3 = ha == 3 ? ca : 0.f;
      float p0 = mk ? ELEM(v0m, e) : ELEM(v0a, e);
      float p1 = mk ? ELEM(v1m, e) : ELEM(v1a, e);
      acc[0][0] = fmaf(w0, p0, acc[0][0]); acc[0][1] = fmaf(w1, p0, acc[0][1]);
      acc[0][2] = fmaf(w2, p0, acc[0][2]); acc[0][3] = fmaf(w3, p0, acc[0][3]);
      acc[0][4] = fmaf(u0, p0, acc[0][4]); acc[0][5] = fmaf(u1, p0, acc[0][5]);
      acc[0][6] = fmaf(u2, p0, acc[0][6]); acc[0][7] = fmaf(u3, p0, acc[0][7]);
      acc[1][0] = fmaf(w0, p1, acc[1][0]); acc[1][1] = fmaf(w1, p1, acc[1][1]);
      acc[1][2] = fmaf(w2, p1, acc[1][2]); acc[1][3] = fmaf(w3, p1, acc[1][3]);
      acc[1][4] = fmaf(u0, p1, acc[1][4]); acc[1][5] = fmaf(u1, p1, acc[1][5]);
      acc[1][6] = fmaf(u2, p1, acc[1][6]); acc[1][7] = fmaf(u3, p1, acc[1][7]);
    }
  }

#pragma unroll
  for (int c = 0; c < 2; ++c)
#pragma unroll
    for (int j = 0; j < 8; ++j) {
      float v = wave_sum64(acc[c][j]);
      if (lane == 0) {
        int map = j >> 2, cls = j & 3;
        atomicAdd(&sums[((map * NB + b) * NC + cls) * ND + ch0 + c], v);
      }
    }
}

// -------- Pass C: finalize centers + norms (1 block) --------
__global__ __launch_bounds__(1024) void passC(
    const float* __restrict__ sums, const float* __restrict__ counts,
    float* __restrict__ centers, float* __restrict__ cnorm) {
  int t = threadIdx.x;
  int g = t >> 5;
  float cv = sums[t] / fmaxf(counts[g], 1.f);
  centers[t] = cv;
  float s = cv * cv;
#pragma unroll
  for (int off = 16; off > 0; off >>= 1) s += __shfl_xor(s, off, 32);
  if ((t & 31) == 0) cnorm[g] = fmaxf(sqrtf(s), EPSF);
}

// -------- Pass D (bf16 pf path): (256,2) + unroll 8 (no spill) --------
__global__ __launch_bounds__(256, 2) void passDpf(
    const unsigned short* __restrict__ pf, const unsigned* __restrict__ recu,
    const float4* __restrict__ cem4, const float4* __restrict__ cea4,
    const float* __restrict__ centers, const float* __restrict__ cnorm,
    float* __restrict__ part) {
  __shared__ float sc[1024];
  __shared__ float scn[32];
  __shared__ float red[4][4];
  for (int i = threadIdx.x; i < 1024; i += 256) {
    int d = i & 31, cls = (i >> 5) & 3, bb = (i >> 7) & 3, mp = i >> 9;
    sc[d * 32 + mp * 16 + bb * 4 + cls] = centers[i];
  }
  if (threadIdx.x < 32) scn[threadIdx.x] = cnorm[threadIdx.x];
  __syncthreads();

  int p4 = blockIdx.x * 256 + threadIdx.x;
  int b = p4 >> 16;
  int px4 = p4 & 0xFFFF;
  unsigned ru = recu[p4];
  int im[4], ia[4];
#pragma unroll
  for (int e = 0; e < 4; ++e) {
    unsigned r = (ru >> (8 * e)) & 0xffu;
    im[e] = b * 4 + (r & 3);
    ia[e] = 16 + b * 4 + ((r >> 2) & 3);
  }
  const ushort4* pfb = (const ushort4*)pf + (((long)(b * ND)) << 16) + px4;
  float4 nm = {0.f, 0.f, 0.f, 0.f}, na = {0.f, 0.f, 0.f, 0.f},
         fn2 = {0.f, 0.f, 0.f, 0.f};
#pragma unroll 8
  for (int d = 0; d < ND; ++d) {
    ushort4 v = pfb[(long)d << 16];
#pragma unroll
    for (int e = 0; e < 4; ++e) {
      float ps = bf2f(e == 0 ? v.x : e == 1 ? v.y : e == 2 ? v.z : v.w);
      float cim = sc[d * 32 + im[e]];
      float cia = sc[d * 32 + ia[e]];
      if (e == 0) { nm.x = fmaf(ps, cim, nm.x); na.x = fmaf(ps, cia, na.x); fn2.x = fmaf(ps, ps, fn2.x); }
      if (e == 1) { nm.y = fmaf(ps, cim, nm.y); na.y = fmaf(ps, cia, na.y); fn2.y = fmaf(ps, ps, fn2.y); }
      if (e == 2) { nm.z = fmaf(ps, cim, nm.z); na.z = fmaf(ps, cia, na.z); fn2.z = fmaf(ps, ps, fn2.z); }
      if (e == 3) { nm.w = fmaf(ps, cim, nm.w); na.w = fmaf(ps, cia, na.w); fn2.w = fmaf(ps, ps, fn2.w); }
    }
  }
  float4 cem = cem4[p4], cea = cea4[p4];
  float s0 = 0.f, s1 = 0.f, s2 = 0.f, s3 = 0.f;
#pragma unroll
  for (int e = 0; e < 4; ++e) {
    float fn = fmaxf(sqrtf(ELEM(fn2, e)), EPSF);
    float rm = ELEM(nm, e) / (fn * scn[im[e]]);
    float ra = ELEM(na, e) / (fn * scn[ia[e]]);
    s0 = fmaf(ELEM(cem, e), ra, s0);
    s1 += ra;
    s2 = fmaf(ELEM(cea, e), rm, s2);
    s3 += rm;
  }
  s0 = wave_sum64(s0); s1 = wave_sum64(s1);
  s2 = wave_sum64(s2); s3 = wave_sum64(s3);
  int wave = threadIdx.x >> 6, lane = threadIdx.x & 63;
  if (lane == 0) { red[wave][0] = s0; red[wave][1] = s1; red[wave][2] = s2; red[wave][3] = s3; }
  __syncthreads();
  if (threadIdx.x < 4) {
    float v = red[0][threadIdx.x] + red[1][threadIdx.x] +
              red[2][threadIdx.x] + red[3][threadIdx.x];
    atomicAdd(&part[(blockIdx.x & 63) * 4 + threadIdx.x], v);
  }
}

// -------- Pass D (f32 fallback) --------
__global__ __launch_bounds__(256) void passDf32(
    const float* __restrict__ fm, const float* __restrict__ fa,
    const unsigned* __restrict__ recu, const float4* __restrict__ cem4,
    const float4* __restrict__ cea4, const float* __restrict__ centers,
    const float* __restrict__ cnorm, float* __restrict__ part) {
  __shared__ float sc[1024];
  __shared__ float scn[32];
  __shared__ float red[4][4];
  for (int i = threadIdx.x; i < 1024; i += 256) {
    int d = i & 31, cls = (i >> 5) & 3, bb = (i >> 7) & 3, mp = i >> 9;
    sc[d * 32 + mp * 16 + bb * 4 + cls] = centers[i];
  }
  if (threadIdx.x < 32) scn[threadIdx.x] = cnorm[threadIdx.x];
  __syncthreads();

  int p4 = blockIdx.x * 256 + threadIdx.x;
  int b = p4 >> 16;
  int px4 = p4 & 0xFFFF;
  unsigned ru = recu[p4];
  int im[4], ia[4], mk[4];
#pragma unroll
  for (int e = 0; e < 4; ++e) {
    unsigned r = (ru >> (8 * e)) & 0xffu;
    im[e] = b * 4 + (r & 3);
    ia[e] = 16 + b * 4 + ((r >> 2) & 3);
    mk[e] = (r >> 4) & 1;
  }
  const float4* fmb = (const float4*)fm + (((long)(b * ND)) << 16) + px4;
  const float4* fab = (const float4*)fa + (((long)(b * ND)) << 16) + px4;
  float4 nm = {0.f, 0.f, 0.f, 0.f}, na = {0.f, 0.f, 0.f, 0.f},
         fn2 = {0.f, 0.f, 0.f, 0.f};
#pragma unroll 16
  for (int d = 0; d < ND; ++d) {
    float4 vm = fmb[(long)d << 16];
    float4 va = fab[(long)d << 16];
#pragma unroll
    for (int e = 0; e < 4; ++e) {
      float ps = mk[e] ? ELEM(vm, e) : ELEM(va, e);
      float cim = sc[d * 32 + im[e]];
      float cia = sc[d * 32 + ia[e]];
      if (e == 0) { nm.x = fmaf(ps, cim, nm.x); na.x = fmaf(ps, cia, na.x); fn2.x = fmaf(ps, ps, fn2.x); }
      if (e == 1) { nm.y = fmaf(ps, cim, nm.y); na.y = fmaf(ps, cia, na.y); fn2.y = fmaf(ps, ps, fn2.y); }
      if (e == 2) { nm.z = fmaf(ps, cim, nm.z); na.z = fmaf(ps, cia, na.z); fn2.z = fmaf(ps, ps, fn2.z); }
      if (e == 3) { nm.w = fmaf(ps, cim, nm.w); na.w = fmaf(ps, cia, na.w); fn2.w = fmaf(ps, ps, fn2.w); }
    }
  }
  float4 cem = cem4[p4], cea = cea4[p4];
  float s0 = 0.f, s1 = 0.f, s2 = 0.f, s3 = 0.f;
#pragma unroll
  for (int e = 0; e < 4; ++e) {
    float fn = fmaxf(sqrtf(ELEM(fn2, e)), EPSF);
    float rm = ELEM(nm, e) / (fn * scn[im[e]]);
    float ra = ELEM(na, e) / (fn * scn[ia[e]]);
    s0 = fmaf(ELEM(cem, e), ra, s0);
    s1 += ra;
    s2 = fmaf(ELEM(cea, e), rm, s2);
    s3 += rm;
  }
  s0 = wave_sum64(s0); s1 = wave_sum64(s1);
  s2 = wave_sum64(s2); s3 = wave_sum64(s3);
  int wave = threadIdx.x >> 6, lane = threadIdx.x & 63;
  if (lane == 0) { red[wave][0] = s0; red[wave][1] = s1; red[wave][2] = s2; red[wave][3] = s3; }
  __syncthreads();
  if (threadIdx.x < 4) {
    float v = red[0][threadIdx.x] + red[1][threadIdx.x] +
              red[2][threadIdx.x] + red[3][threadIdx.x];
    atomicAdd(&part[(blockIdx.x & 63) * 4 + threadIdx.x], v);
  }
}

// -------- Pass E: final scalar --------
__global__ __launch_bounds__(64) void passE(const float* __restrict__ part,
                                            float* __restrict__ out) {
  int t = threadIdx.x;
  float a0 = part[t * 4 + 0], a1 = part[t * 4 + 1];
  float a2 = part[t * 4 + 2], a3 = part[t * 4 + 3];
  a0 = wave_sum64(a0); a1 = wave_sum64(a1);
  a2 = wave_sum64(a2); a3 = wave_sum64(a3);
  if (t == 0) out[0] = a0 / a1 + a2 / a3;
}

extern "C" void kernel_launch(void* const* d_in, const int* in_sizes, int n_in,
                              void* d_out, int out_size, void* d_ws, size_t ws_size,
                              hipStream_t stream) {
  const float* pm = (const float*)d_in[0];
  const float* pa = (const float*)d_in[1];
  const float* fm = (const float*)d_in[2];
  const float* fa = (const float*)d_in[3];

  float* wsf = (float*)d_ws;
  float* sums = wsf + OFF_SUMS;
  float* counts = wsf + OFF_COUNTS;
  float* centers = wsf + OFF_CENTERS;
  float* cnorm = wsf + OFF_CNORM;
  float* part = wsf + OFF_PART;
  char* wsb = (char*)d_ws;
  unsigned* recu = (unsigned*)(wsb + OFF_REC);
  uint4* cpk4 = (uint4*)(wsb + OFF_CPK);
  float4* cem4 = (float4*)(wsb + OFF_CEM);
  float4* cea4 = (float4*)(wsb + OFF_CEA);
  unsigned short* pf = (unsigned short*)(wsb + OFF_PF);
  bool use_pf = ws_size >= (size_t)WS_NEED_PF;

  hipMemsetAsync(d_ws, 0, HDR_BYTES, stream);
  passA2s<<<1024, 256, 0, stream>>>(pm, pa, recu, cpk4, cem4, cea4);
  countK<<<dim3(32, 4), 256, 0, stream>>>(recu, counts);
  if (use_pf) {
    pfWrite<<<1024, 256, 0, stream>>>(fm, fa, recu, pf);
    passBpf<<<dim3(128, 16), 256, 0, stream>>>(pf, recu, cpk4, sums);
    passC<<<1, 1024, 0, stream>>>(sums, counts, centers, cnorm);
    passDpf<<<1024, 256, 0, stream>>>(pf, recu, cem4, cea4, centers, cnorm,
                                      part);
  } else {
    passBf32<<<dim3(128, 16), 256, 0, stream>>>(fm, fa, recu, cpk4, sums);
    passC<<<1, 1024, 0, stream>>>(sums, counts, centers, cnorm);
    passDf32<<<1024, 256, 0, stream>>>(fm, fa, recu, cem4, cea4, centers,
                                       cnorm, part);
  }
  passE<<<1, 64, 0, stream>>>(part, (float*)d_out);
}

// Round 9
// 180.474 us; speedup vs baseline: 1.4011x; 1.4011x over previous
//
#include <hip/hip_runtime.h>
#include <math.h>

#define HW 262144          // 512*512
#define NB 4
#define NC 4
#define ND 32
#define NPIX (NB * HW)     // 1048576
#define NG 262144          // float4 pixel-groups (NPIX/4)
#define EPSF 1e-8f

// ws header (floats):
#define OFF_SUMS    0      // 1024
#define OFF_COUNTS  1024   // 32
#define OFF_CENTERS 1056   // 1024
#define OFF_CNORM   2080   // 32
#define OFF_PART    2112   // 256
#define HDR_BYTES   9472
// byte offsets after header:
#define OFF_REC     HDR_BYTES                     // u32[NG]    1 MB
#define OFF_CPK     (OFF_REC + 4L * NG)           // uint4[NG]  4 MB (bf16 conf pairs)
#define OFF_CEM     (OFF_CPK + 16L * NG)          // float4[NG] 4 MB
#define OFF_CEA     (OFF_CEM + 16L * NG)          // float4[NG] 4 MB
#define OFF_PF      (OFF_CEA + 16L * NG)          // bf16 [b][d][px] 64 MB
#define WS_NEED_PF  (OFF_PF + 2L * NB * ND * HW)  // ~77 MB

#define ELEM(v,e) ((e)==0?(v).x:(e)==1?(v).y:(e)==2?(v).z:(v).w)
#define W32(q,i)  ((i)==0?(q).x:(i)==1?(q).y:(i)==2?(q).z:(q).w)

__device__ __forceinline__ float wave_sum64(float v) {
#pragma unroll
  for (int off = 32; off > 0; off >>= 1) v += __shfl_xor(v, off, 64);
  return v;
}
__device__ __forceinline__ unsigned short f2bf(float f) {  // RNE
  unsigned u = __float_as_uint(f);
  return (unsigned short)((u + 0x7fffu + ((u >> 16) & 1u)) >> 16);
}
__device__ __forceinline__ float bf2f(unsigned short s) {
  return __uint_as_float(((unsigned)s) << 16);
}

// -------- Pass A2s: per-pixel stats only (R2-proven shape) --------
__global__ __launch_bounds__(256) void passA2s(
    const float* __restrict__ pm, const float* __restrict__ pa,
    unsigned* __restrict__ recu, uint4* __restrict__ cpk4,
    float4* __restrict__ cem4, float4* __restrict__ cea4) {
  int p4 = blockIdx.x * 256 + threadIdx.x;
  int b = p4 >> 16;
  int px4 = p4 & 0xFFFF;
  const float4* xb = (const float4*)pm + (((long)b * NC) << 16) + px4;
  const float4* yb = (const float4*)pa + (((long)b * NC) << 16) + px4;
  float4 X0 = xb[0], X1 = xb[1 << 16], X2 = xb[2 << 16], X3 = xb[3 << 16];
  float4 Y0 = yb[0], Y1 = yb[1 << 16], Y2 = yb[2 << 16], Y3 = yb[3 << 16];
  float4 cem, cea;
  uint4 cpk;
  unsigned ru = 0;
#pragma unroll
  for (int e = 0; e < 4; ++e) {
    float x0 = ELEM(X0, e), x1 = ELEM(X1, e), x2 = ELEM(X2, e), x3 = ELEM(X3, e);
    float y0 = ELEM(Y0, e), y1 = ELEM(Y1, e), y2 = ELEM(Y2, e), y3 = ELEM(Y3, e);
    int hm = 0; float bm = x0;
    if (x1 > bm) { bm = x1; hm = 1; }
    if (x2 > bm) { bm = x2; hm = 2; }
    if (x3 > bm) { bm = x3; hm = 3; }
    int ha = 0; float ba = y0;
    if (y1 > ba) { ba = y1; ha = 1; }
    if (y2 > ba) { ba = y2; ha = 2; }
    if (y3 > ba) { ba = y3; ha = 3; }
    float sem = expf(x0 - bm) + expf(x1 - bm) + expf(x2 - bm) + expf(x3 - bm);
    float sea = expf(y0 - ba) + expf(y1 - ba) + expf(y2 - ba) + expf(y3 - ba);
    float confm = 1.0f / sem, confa = 1.0f / sea;
    int mk = (confm >= confa) ? 1 : 0;
    int lab = mk ? hm : ha;
    float xl = lab == 0 ? x0 : lab == 1 ? x1 : lab == 2 ? x2 : x3;
    float yl = lab == 0 ? y0 : lab == 1 ? y1 : lab == 2 ? y2 : y3;
    float vem = bm - xl + logf(sem);
    float vea = ba - yl + logf(sea);
    unsigned pk = (unsigned)f2bf(confm) | ((unsigned)f2bf(confa) << 16);
    if (e == 0) { cem.x = vem; cea.x = vea; cpk.x = pk; }
    if (e == 1) { cem.y = vem; cea.y = vea; cpk.y = pk; }
    if (e == 2) { cem.z = vem; cea.z = vea; cpk.z = pk; }
    if (e == 3) { cem.w = vem; cea.w = vea; cpk.w = pk; }
    ru |= (unsigned)(hm | (ha << 2) | (mk << 4)) << (8 * e);
  }
  cem4[p4] = cem; cea4[p4] = cea; cpk4[p4] = cpk; recu[p4] = ru;
}

// -------- pfWriteB: stream features -> bf16 pf + center sums fused -------
// Streams fm/fa once (256 MB), writes pf (64 MB), and accumulates the
// confidence-weighted class-center sums in-register (predicated FMA into 8
// bins per lane per d) + wave_sum64 + 4-wave LDS reduce + 256 atomics/block.
// Eliminates the separate B pass (110 us in R8, stall-bound at MLP~1).
__global__ __launch_bounds__(256, 2) void pfWriteB(
    const float* __restrict__ fm, const float* __restrict__ fa,
    const unsigned* __restrict__ recu, const uint4* __restrict__ cpk4,
    unsigned short* __restrict__ pf, float* __restrict__ sums) {
  __shared__ float lred[4][256];    // [wave][d*8 + map*4 + cls]
  int p4 = blockIdx.x * 256 + threadIdx.x;
  int b = blockIdx.x >> 8;          // 256 blocks per batch; uniform per block
  int px4 = p4 & 0xFFFF;
  int wave = threadIdx.x >> 6, lane = threadIdx.x & 63;

  unsigned ru = recu[p4];
  uint4 ck = cpk4[p4];
  int mk0 = (ru >> 4) & 1, mk1 = (ru >> 12) & 1;
  int mk2 = (ru >> 20) & 1, mk3 = (ru >> 28) & 1;
  // precompute per-(pixel, class) weights (constant-indexed, SROA-safe)
  float wmw[4][4], waw[4][4];
#pragma unroll
  for (int e = 0; e < 4; ++e) {
    unsigned r = (ru >> (8 * e)) & 0xffu;
    unsigned pk = W32(ck, e);
    int hm = r & 3, ha = (r >> 2) & 3;
    float cm = __uint_as_float(pk << 16);
    float ca = __uint_as_float(pk & 0xffff0000u);
#pragma unroll
    for (int c = 0; c < 4; ++c) {
      wmw[e][c] = (hm == c) ? cm : 0.f;
      waw[e][c] = (ha == c) ? ca : 0.f;
    }
  }

  const float4* fmb = (const float4*)fm + (((long)(b * ND)) << 16) + px4;
  const float4* fab = (const float4*)fa + (((long)(b * ND)) << 16) + px4;
  ushort4* pfb = (ushort4*)pf + (((long)(b * ND)) << 16) + px4;

#pragma unroll 2
  for (int d = 0; d < ND; ++d) {
    float4 vm = fmb[(long)d << 16];
    float4 va = fab[(long)d << 16];
    float ps0 = mk0 ? vm.x : va.x;
    float ps1 = mk1 ? vm.y : va.y;
    float ps2 = mk2 ? vm.z : va.z;
    float ps3 = mk3 ? vm.w : va.w;
    ushort4 s;
    s.x = f2bf(ps0); s.y = f2bf(ps1); s.z = f2bf(ps2); s.w = f2bf(ps3);
    pfb[(long)d << 16] = s;
    // 8 bins for this d: map*4+cls
    float pp[8];
#pragma unroll
    for (int c = 0; c < 4; ++c) {
      pp[c]     = fmaf(wmw[0][c], ps0, fmaf(wmw[1][c], ps1,
                  fmaf(wmw[2][c], ps2, wmw[3][c] * ps3)));
      pp[4 + c] = fmaf(waw[0][c], ps0, fmaf(waw[1][c], ps1,
                  fmaf(waw[2][c], ps2, waw[3][c] * ps3)));
    }
#pragma unroll
    for (int j = 0; j < 8; ++j) {
      float r = wave_sum64(pp[j]);
      if (lane == 0) lred[wave][d * 8 + j] = r;
    }
  }
  __syncthreads();
  {
    int t = threadIdx.x;            // t = d*8 + j
    float v = lred[0][t] + lred[1][t] + lred[2][t] + lred[3][t];
    int d = t >> 3, j = t & 7;
    int map = j >> 2, cls = j & 3;
    atomicAdd(&sums[((map * NB + b) * NC + cls) * ND + d], v);
  }
}

// -------- countK: per-(b,map,cls) pixel counts from recu --------
__global__ __launch_bounds__(256) void countK(const unsigned* __restrict__ recu,
                                              float* __restrict__ counts) {
  int b = blockIdx.y;
  int t = blockIdx.x * 256 + threadIdx.x;   // grid.x=32 -> t in [0,8192)
  float c[8];
#pragma unroll
  for (int j = 0; j < 8; ++j) c[j] = 0.f;
#pragma unroll
  for (int k = 0; k < 8; ++k) {
    unsigned ru = recu[(b << 16) + t + k * 8192];
#pragma unroll
    for (int e = 0; e < 4; ++e) {
      unsigned r = (ru >> (8 * e)) & 0xffu;
      int hm = r & 3, ha = (r >> 2) & 3;
      c[0] += hm == 0 ? 1.f : 0.f; c[1] += hm == 1 ? 1.f : 0.f;
      c[2] += hm == 2 ? 1.f : 0.f; c[3] += hm == 3 ? 1.f : 0.f;
      c[4] += ha == 0 ? 1.f : 0.f; c[5] += ha == 1 ? 1.f : 0.f;
      c[6] += ha == 2 ? 1.f : 0.f; c[7] += ha == 3 ? 1.f : 0.f;
    }
  }
  int lane = threadIdx.x & 63;
#pragma unroll
  for (int j = 0; j < 8; ++j) {
    float v = wave_sum64(c[j]);
    if (lane == 0) atomicAdd(&counts[(j >> 2) * 16 + b * 4 + (j & 3)], v);
  }
}

// -------- Pass B (f32 fallback): R2-proven structure (counts via countK) --
__global__ __launch_bounds__(256) void passBf32(
    const float* __restrict__ fm, const float* __restrict__ fa,
    const unsigned* __restrict__ recu, const uint4* __restrict__ cpk4,
    float* __restrict__ sums) {
  int b = blockIdx.y >> 2;
  int cg = blockIdx.y & 3;
  int wave = threadIdx.x >> 6;
  int lane = threadIdx.x & 63;
  int ch0 = cg * 8 + wave * 2;

  int base4 = blockIdx.x * 512 + lane;
  const float4* f0m = (const float4*)fm + (((long)(b * ND + ch0)) << 16) + base4;
  const float4* f0a = (const float4*)fa + (((long)(b * ND + ch0)) << 16) + base4;
  const float4* f1m = f0m + (1L << 16);
  const float4* f1a = f0a + (1L << 16);
  const unsigned* rup = recu + (b << 16) + base4;
  const uint4* cpp = cpk4 + (b << 16) + base4;

  float acc[2][8];
#pragma unroll
  for (int c = 0; c < 2; ++c)
#pragma unroll
    for (int j = 0; j < 8; ++j) acc[c][j] = 0.f;

#pragma unroll 2
  for (int it = 0; it < 8; ++it) {
    int i4 = it * 64;
    unsigned ru = rup[i4];
    uint4 ck = cpp[i4];
    float4 v0m = f0m[i4], v0a = f0a[i4];
    float4 v1m = f1m[i4], v1a = f1a[i4];
#pragma unroll
    for (int e = 0; e < 4; ++e) {
      unsigned r = (ru >> (8 * e)) & 0xffu;
      unsigned pk = W32(ck, e);
      int hm = r & 3, ha = (r >> 2) & 3, mk = (r >> 4) & 1;
      float cm = __uint_as_float(pk << 16);
      float ca = __uint_as_float(pk & 0xffff0000u);
      float w0 = hm == 0 ? cm : 0.f, w1 = hm == 1 ? cm : 0.f;
      float w2 = hm == 2 ? cm : 0.f, w3 = hm == 3 ? cm : 0.f;
      float u0 = ha == 0 ? ca : 0.f, u1 = ha == 1 ? ca : 0.f;
      float u2 = ha == 2 ? ca : 0.f, u3 = ha == 3 ? ca : 0.f;
      float p0 = mk ? ELEM(v0m, e) : ELEM(v0a, e);
      float p1 = mk ? ELEM(v1m, e) : ELEM(v1a, e);
      acc[0][0] = fmaf(w0, p0, acc[0][0]); acc[0][1] = fmaf(w1, p0, acc[0][1]);
      acc[0][2] = fmaf(w2, p0, acc[0][2]); acc[0][3] = fmaf(w3, p0, acc[0][3]);
      acc[0][4] = fmaf(u0, p0, acc[0][4]); acc[0][5] = fmaf(u1, p0, acc[0][5]);
      acc[0][6] = fmaf(u2, p0, acc[0][6]); acc[0][7] = fmaf(u3, p0, acc[0][7]);
      acc[1][0] = fmaf(w0, p1, acc[1][0]); acc[1][1] = fmaf(w1, p1, acc[1][1]);
      acc[1][2] = fmaf(w2, p1, acc[1][2]); acc[1][3] = fmaf(w3, p1, acc[1][3]);
      acc[1][4] = fmaf(u0, p1, acc[1][4]); acc[1][5] = fmaf(u1, p1, acc[1][5]);
      acc[1][6] = fmaf(u2, p1, acc[1][6]); acc[1][7] = fmaf(u3, p1, acc[1][7]);
    }
  }

#pragma unroll
  for (int c = 0; c < 2; ++c)
#pragma unroll
    for (int j = 0; j < 8; ++j) {
      float v = wave_sum64(acc[c][j]);
      if (lane == 0) {
        int map = j >> 2, cls = j & 3;
        atomicAdd(&sums[((map * NB + b) * NC + cls) * ND + ch0 + c], v);
      }
    }
}

// -------- Pass C: finalize centers + norms (1 block) --------
__global__ __launch_bounds__(1024) void passC(
    const float* __restrict__ sums, const float* __restrict__ counts,
    float* __restrict__ centers, float* __restrict__ cnorm) {
  int t = threadIdx.x;
  int g = t >> 5;
  float cv = sums[t] / fmaxf(counts[g], 1.f);
  centers[t] = cv;
  float s = cv * cv;
#pragma unroll
  for (int off = 16; off > 0; off >>= 1) s += __shfl_xor(s, off, 32);
  if ((t & 31) == 0) cnorm[g] = fmaxf(sqrtf(s), EPSF);
}

// -------- Pass D (bf16 pf path): (256,2) + unroll 8 --------
__global__ __launch_bounds__(256, 2) void passDpf(
    const unsigned short* __restrict__ pf, const unsigned* __restrict__ recu,
    const float4* __restrict__ cem4, const float4* __restrict__ cea4,
    const float* __restrict__ centers, const float* __restrict__ cnorm,
    float* __restrict__ part) {
  __shared__ float sc[1024];
  __shared__ float scn[32];
  __shared__ float red[4][4];
  for (int i = threadIdx.x; i < 1024; i += 256) {
    int d = i & 31, cls = (i >> 5) & 3, bb = (i >> 7) & 3, mp = i >> 9;
    sc[d * 32 + mp * 16 + bb * 4 + cls] = centers[i];
  }
  if (threadIdx.x < 32) scn[threadIdx.x] = cnorm[threadIdx.x];
  __syncthreads();

  int p4 = blockIdx.x * 256 + threadIdx.x;
  int b = p4 >> 16;
  int px4 = p4 & 0xFFFF;
  unsigned ru = recu[p4];
  int im[4], ia[4];
#pragma unroll
  for (int e = 0; e < 4; ++e) {
    unsigned r = (ru >> (8 * e)) & 0xffu;
    im[e] = b * 4 + (r & 3);
    ia[e] = 16 + b * 4 + ((r >> 2) & 3);
  }
  const ushort4* pfb = (const ushort4*)pf + (((long)(b * ND)) << 16) + px4;
  float4 nm = {0.f, 0.f, 0.f, 0.f}, na = {0.f, 0.f, 0.f, 0.f},
         fn2 = {0.f, 0.f, 0.f, 0.f};
#pragma unroll 8
  for (int d = 0; d < ND; ++d) {
    ushort4 v = pfb[(long)d << 16];
#pragma unroll
    for (int e = 0; e < 4; ++e) {
      float ps = bf2f(e == 0 ? v.x : e == 1 ? v.y : e == 2 ? v.z : v.w);
      float cim = sc[d * 32 + im[e]];
      float cia = sc[d * 32 + ia[e]];
      if (e == 0) { nm.x = fmaf(ps, cim, nm.x); na.x = fmaf(ps, cia, na.x); fn2.x = fmaf(ps, ps, fn2.x); }
      if (e == 1) { nm.y = fmaf(ps, cim, nm.y); na.y = fmaf(ps, cia, na.y); fn2.y = fmaf(ps, ps, fn2.y); }
      if (e == 2) { nm.z = fmaf(ps, cim, nm.z); na.z = fmaf(ps, cia, na.z); fn2.z = fmaf(ps, ps, fn2.z); }
      if (e == 3) { nm.w = fmaf(ps, cim, nm.w); na.w = fmaf(ps, cia, na.w); fn2.w = fmaf(ps, ps, fn2.w); }
    }
  }
  float4 cem = cem4[p4], cea = cea4[p4];
  float s0 = 0.f, s1 = 0.f, s2 = 0.f, s3 = 0.f;
#pragma unroll
  for (int e = 0; e < 4; ++e) {
    float fn = fmaxf(sqrtf(ELEM(fn2, e)), EPSF);
    float rm = ELEM(nm, e) / (fn * scn[im[e]]);
    float ra = ELEM(na, e) / (fn * scn[ia[e]]);
    s0 = fmaf(ELEM(cem, e), ra, s0);
    s1 += ra;
    s2 = fmaf(ELEM(cea, e), rm, s2);
    s3 += rm;
  }
  s0 = wave_sum64(s0); s1 = wave_sum64(s1);
  s2 = wave_sum64(s2); s3 = wave_sum64(s3);
  int wave = threadIdx.x >> 6, lane = threadIdx.x & 63;
  if (lane == 0) { red[wave][0] = s0; red[wave][1] = s1; red[wave][2] = s2; red[wave][3] = s3; }
  __syncthreads();
  if (threadIdx.x < 4) {
    float v = red[0][threadIdx.x] + red[1][threadIdx.x] +
              red[2][threadIdx.x] + red[3][threadIdx.x];
    atomicAdd(&part[(blockIdx.x & 63) * 4 + threadIdx.x], v);
  }
}

// -------- Pass D (f32 fallback) --------
__global__ __launch_bounds__(256) void passDf32(
    const float* __restrict__ fm, const float* __restrict__ fa,
    const unsigned* __restrict__ recu, const float4* __restrict__ cem4,
    const float4* __restrict__ cea4, const float* __restrict__ centers,
    const float* __restrict__ cnorm, float* __restrict__ part) {
  __shared__ float sc[1024];
  __shared__ float scn[32];
  __shared__ float red[4][4];
  for (int i = threadIdx.x; i < 1024; i += 256) {
    int d = i & 31, cls = (i >> 5) & 3, bb = (i >> 7) & 3, mp = i >> 9;
    sc[d * 32 + mp * 16 + bb * 4 + cls] = centers[i];
  }
  if (threadIdx.x < 32) scn[threadIdx.x] = cnorm[threadIdx.x];
  __syncthreads();

  int p4 = blockIdx.x * 256 + threadIdx.x;
  int b = p4 >> 16;
  int px4 = p4 & 0xFFFF;
  unsigned ru = recu[p4];
  int im[4], ia[4], mk[4];
#pragma unroll
  for (int e = 0; e < 4; ++e) {
    unsigned r = (ru >> (8 * e)) & 0xffu;
    im[e] = b * 4 + (r & 3);
    ia[e] = 16 + b * 4 + ((r >> 2) & 3);
    mk[e] = (r >> 4) & 1;
  }
  const float4* fmb = (const float4*)fm + (((long)(b * ND)) << 16) + px4;
  const float4* fab = (const float4*)fa + (((long)(b * ND)) << 16) + px4;
  float4 nm = {0.f, 0.f, 0.f, 0.f}, na = {0.f, 0.f, 0.f, 0.f},
         fn2 = {0.f, 0.f, 0.f, 0.f};
#pragma unroll 16
  for (int d = 0; d < ND; ++d) {
    float4 vm = fmb[(long)d << 16];
    float4 va = fab[(long)d << 16];
#pragma unroll
    for (int e = 0; e < 4; ++e) {
      float ps = mk[e] ? ELEM(vm, e) : ELEM(va, e);
      float cim = sc[d * 32 + im[e]];
      float cia = sc[d * 32 + ia[e]];
      if (e == 0) { nm.x = fmaf(ps, cim, nm.x); na.x = fmaf(ps, cia, na.x); fn2.x = fmaf(ps, ps, fn2.x); }
      if (e == 1) { nm.y = fmaf(ps, cim, nm.y); na.y = fmaf(ps, cia, na.y); fn2.y = fmaf(ps, ps, fn2.y); }
      if (e == 2) { nm.z = fmaf(ps, cim, nm.z); na.z = fmaf(ps, cia, na.z); fn2.z = fmaf(ps, ps, fn2.z); }
      if (e == 3) { nm.w = fmaf(ps, cim, nm.w); na.w = fmaf(ps, cia, na.w); fn2.w = fmaf(ps, ps, fn2.w); }
    }
  }
  float4 cem = cem4[p4], cea = cea4[p4];
  float s0 = 0.f, s1 = 0.f, s2 = 0.f, s3 = 0.f;
#pragma unroll
  for (int e = 0; e < 4; ++e) {
    float fn = fmaxf(sqrtf(ELEM(fn2, e)), EPSF);
    float rm = ELEM(nm, e) / (fn * scn[im[e]]);
    float ra = ELEM(na, e) / (fn * scn[ia[e]]);
    s0 = fmaf(ELEM(cem, e), ra, s0);
    s1 += ra;
    s2 = fmaf(ELEM(cea, e), rm, s2);
    s3 += rm;
  }
  s0 = wave_sum64(s0); s1 = wave_sum64(s1);
  s2 = wave_sum64(s2); s3 = wave_sum64(s3);
  int wave = threadIdx.x >> 6, lane = threadIdx.x & 63;
  if (lane == 0) { red[wave][0] = s0; red[wave][1] = s1; red[wave][2] = s2; red[wave][3] = s3; }
  __syncthreads();
  if (threadIdx.x < 4) {
    float v = red[0][threadIdx.x] + red[1][threadIdx.x] +
              red[2][threadIdx.x] + red[3][threadIdx.x];
    atomicAdd(&part[(blockIdx.x & 63) * 4 + threadIdx.x], v);
  }
}

// -------- Pass E: final scalar --------
__global__ __launch_bounds__(64) void passE(const float* __restrict__ part,
                                            float* __restrict__ out) {
  int t = threadIdx.x;
  float a0 = part[t * 4 + 0], a1 = part[t * 4 + 1];
  float a2 = part[t * 4 + 2], a3 = part[t * 4 + 3];
  a0 = wave_sum64(a0); a1 = wave_sum64(a1);
  a2 = wave_sum64(a2); a3 = wave_sum64(a3);
  if (t == 0) out[0] = a0 / a1 + a2 / a3;
}

extern "C" void kernel_launch(void* const* d_in, const int* in_sizes, int n_in,
                              void* d_out, int out_size, void* d_ws, size_t ws_size,
                              hipStream_t stream) {
  const float* pm = (const float*)d_in[0];
  const float* pa = (const float*)d_in[1];
  const float* fm = (const float*)d_in[2];
  const float* fa = (const float*)d_in[3];

  float* wsf = (float*)d_ws;
  float* sums = wsf + OFF_SUMS;
  float* counts = wsf + OFF_COUNTS;
  float* centers = wsf + OFF_CENTERS;
  float* cnorm = wsf + OFF_CNORM;
  float* part = wsf + OFF_PART;
  char* wsb = (char*)d_ws;
  unsigned* recu = (unsigned*)(wsb + OFF_REC);
  uint4* cpk4 = (uint4*)(wsb + OFF_CPK);
  float4* cem4 = (float4*)(wsb + OFF_CEM);
  float4* cea4 = (float4*)(wsb + OFF_CEA);
  unsigned short* pf = (unsigned short*)(wsb + OFF_PF);
  bool use_pf = ws_size >= (size_t)WS_NEED_PF;

  hipMemsetAsync(d_ws, 0, HDR_BYTES, stream);
  passA2s<<<1024, 256, 0, stream>>>(pm, pa, recu, cpk4, cem4, cea4);
  countK<<<dim3(32, 4), 256, 0, stream>>>(recu, counts);
  if (use_pf) {
    pfWriteB<<<1024, 256, 0, stream>>>(fm, fa, recu, cpk4, pf, sums);
    passC<<<1, 1024, 0, stream>>>(sums, counts, centers, cnorm);
    passDpf<<<1024, 256, 0, stream>>>(pf, recu, cem4, cea4, centers, cnorm,
                                      part);
  } else {
    passBf32<<<dim3(128, 16), 256, 0, stream>>>(fm, fa, recu, cpk4, sums);
    passC<<<1, 1024, 0, stream>>>(sums, counts, centers, cnorm);
    passDf32<<<1024, 256, 0, stream>>>(fm, fa, recu, cem4, cea4, centers,
                                       cnorm, part);
  }
  passE<<<1, 64, 0, stream>>>(part, (float*)d_out);
}